// Round 1
// baseline (1103.301 us; speedup 1.0000x reference)
//
#include <hip/hip_runtime.h>
#include <math.h>

// Problem constants
#define BB 8
#define DD 4096
#define SS 16
#define NHH 32
#define FFF 16384
#define DPH 128           // DD/NHH
#define D3 12288          // 3*DD

// ---------------- workspace layout (floats) ----------------
// zeroed region first (single memset):
//   z    [B][3D]   @ 0          (98304)   atomic-accumulated
//   a1   [B][FF]   @ 98304      (131072)  atomic-accumulated
//   a3   [B][FF]   @ 229376     (131072)  atomic-accumulated
// non-zeroed:
//   xn1  [B][D]    @ 360448
//   y    [B][D]    @ 393216
//   xw   [B][D]    @ 425984   seeded with x+out_b by rmsnorm1_k, then atomic-accumulated
//   xn2  [B][D]    @ 458752
#define WS_Z     0
#define WS_A1    98304
#define WS_A3    229376
#define WS_ZERO_COUNT 360448
#define WS_XN1   360448
#define WS_Y     393216
#define WS_XW    425984
#define WS_XN2   458752

// ---------------- rmsnorm (pre) + seed xw = x + out_b ----------------
__global__ __launch_bounds__(256) void rmsnorm1_k(const float* __restrict__ x,
                                                  const float* __restrict__ w,
                                                  const float* __restrict__ out_b,
                                                  float* __restrict__ xn,
                                                  float* __restrict__ xw_seed) {
    const int b = blockIdx.x;
    const int tid = threadIdx.x;
    float ss = 0.f;
    for (int d = tid; d < DD; d += 256) { float v = x[b*DD + d]; ss += v*v; }
    __shared__ float red[4];
    #pragma unroll
    for (int o = 32; o > 0; o >>= 1) ss += __shfl_down(ss, o);
    if ((tid & 63) == 0) red[tid >> 6] = ss;
    __syncthreads();
    float total = red[0] + red[1] + red[2] + red[3];
    float scale = rsqrtf(total / (float)DD + 1e-6f);
    for (int d = tid; d < DD; d += 256) {
        float v = x[b*DD + d];
        xn[b*DD + d] = v * scale * w[d];
        xw_seed[b*DD + d] = v + out_b[d];   // residual + bias seed for out_w GEMV
    }
}

// ---------------- batch-8 GEMV, split-K via atomics, float4 loads ----------------
// W is [N][M] row-major; out[b][M] accumulated atomically (pre-zeroed or pre-seeded).
// 256 threads, each owns 4 consecutive cols (16B loads). grid.x = M/1024, grid.y = N/RPB.
template<int RPB, int M>
__global__ __launch_bounds__(256) void gemv8_k(const float* __restrict__ X,
                                               const float* __restrict__ W,
                                               float* __restrict__ out, int N) {
    __shared__ float xs[BB][RPB];
    const int tid  = threadIdx.x;
    const int col  = blockIdx.x * 1024 + tid * 4;
    const int row0 = blockIdx.y * RPB;
    for (int idx = tid; idx < BB * RPB; idx += 256) {
        int b = idx / RPB, r = idx - b * RPB;
        xs[b][r] = X[b * N + row0 + r];
    }
    __syncthreads();
    float4 acc[BB];
    #pragma unroll
    for (int b = 0; b < BB; ++b) acc[b] = make_float4(0.f, 0.f, 0.f, 0.f);
    const float* Wp = W + (size_t)row0 * M + col;
    for (int r = 0; r < RPB; r += 4) {
        float4 w0 = *(const float4*)(Wp);
        float4 w1 = *(const float4*)(Wp + M);
        float4 w2 = *(const float4*)(Wp + 2 * (size_t)M);
        float4 w3 = *(const float4*)(Wp + 3 * (size_t)M);
        Wp += 4 * (size_t)M;
        #pragma unroll
        for (int b = 0; b < BB; ++b) {
            float4 xv = *(const float4*)&xs[b][r];
            acc[b].x += xv.x*w0.x + xv.y*w1.x + xv.z*w2.x + xv.w*w3.x;
            acc[b].y += xv.x*w0.y + xv.y*w1.y + xv.z*w2.y + xv.w*w3.y;
            acc[b].z += xv.x*w0.z + xv.y*w1.z + xv.z*w2.z + xv.w*w3.z;
            acc[b].w += xv.x*w0.w + xv.y*w1.w + xv.z*w2.w + xv.w*w3.w;
        }
    }
    #pragma unroll
    for (int b = 0; b < BB; ++b) {
        atomicAdd(&out[b * M + col],     acc[b].x);
        atomicAdd(&out[b * M + col + 1], acc[b].y);
        atomicAdd(&out[b * M + col + 2], acc[b].z);
        atomicAdd(&out[b * M + col + 3], acc[b].w);
    }
}

// dual GEMV (mlp_w1 & mlp_w3 share the activation reads), float4 loads
template<int RPB, int M>
__global__ __launch_bounds__(256) void gemv8_dual_k(const float* __restrict__ X,
                                                    const float* __restrict__ W1,
                                                    const float* __restrict__ W3,
                                                    float* __restrict__ o1,
                                                    float* __restrict__ o3, int N) {
    __shared__ float xs[BB][RPB];
    const int tid  = threadIdx.x;
    const int col  = blockIdx.x * 1024 + tid * 4;
    const int row0 = blockIdx.y * RPB;
    for (int idx = tid; idx < BB * RPB; idx += 256) {
        int b = idx / RPB, r = idx - b * RPB;
        xs[b][r] = X[b * N + row0 + r];
    }
    __syncthreads();
    float4 acc1[BB], acc3[BB];
    #pragma unroll
    for (int b = 0; b < BB; ++b) {
        acc1[b] = make_float4(0.f, 0.f, 0.f, 0.f);
        acc3[b] = make_float4(0.f, 0.f, 0.f, 0.f);
    }
    const float* W1p = W1 + (size_t)row0 * M + col;
    const float* W3p = W3 + (size_t)row0 * M + col;
    for (int r = 0; r < RPB; r += 2) {
        float4 u0 = *(const float4*)(W1p);
        float4 u1 = *(const float4*)(W1p + M);
        float4 v0 = *(const float4*)(W3p);
        float4 v1 = *(const float4*)(W3p + M);
        W1p += 2 * (size_t)M;
        W3p += 2 * (size_t)M;
        #pragma unroll
        for (int b = 0; b < BB; ++b) {
            float2 xv = *(const float2*)&xs[b][r];
            acc1[b].x += xv.x*u0.x + xv.y*u1.x;
            acc1[b].y += xv.x*u0.y + xv.y*u1.y;
            acc1[b].z += xv.x*u0.z + xv.y*u1.z;
            acc1[b].w += xv.x*u0.w + xv.y*u1.w;
            acc3[b].x += xv.x*v0.x + xv.y*v1.x;
            acc3[b].y += xv.x*v0.y + xv.y*v1.y;
            acc3[b].z += xv.x*v0.z + xv.y*v1.z;
            acc3[b].w += xv.x*v0.w + xv.y*v1.w;
        }
    }
    #pragma unroll
    for (int b = 0; b < BB; ++b) {
        atomicAdd(&o1[b * M + col],     acc1[b].x);
        atomicAdd(&o1[b * M + col + 1], acc1[b].y);
        atomicAdd(&o1[b * M + col + 2], acc1[b].z);
        atomicAdd(&o1[b * M + col + 3], acc1[b].w);
        atomicAdd(&o3[b * M + col],     acc3[b].x);
        atomicAdd(&o3[b * M + col + 1], acc3[b].y);
        atomicAdd(&o3[b * M + col + 2], acc3[b].z);
        atomicAdd(&o3[b * M + col + 3], acc3[b].w);
    }
}

// mlp_w2 GEMV with silu-gate fused into the staging load:
// xs[b][r] = silu(a1[b][row]) * a3[b][row]; accumulates into pre-seeded out_x.
template<int RPB, int M>
__global__ __launch_bounds__(256) void gemv8_gate_k(const float* __restrict__ A1,
                                                    const float* __restrict__ A3,
                                                    const float* __restrict__ W,
                                                    float* __restrict__ out, int N) {
    __shared__ float xs[BB][RPB];
    const int tid  = threadIdx.x;
    const int col  = blockIdx.x * 1024 + tid * 4;
    const int row0 = blockIdx.y * RPB;
    for (int idx = tid; idx < BB * RPB; idx += 256) {
        int b = idx / RPB, r = idx - b * RPB;
        float v1 = A1[b * N + row0 + r];
        float v3 = A3[b * N + row0 + r];
        xs[b][r] = v3 * (v1 / (1.f + expf(-v1)));
    }
    __syncthreads();
    float4 acc[BB];
    #pragma unroll
    for (int b = 0; b < BB; ++b) acc[b] = make_float4(0.f, 0.f, 0.f, 0.f);
    const float* Wp = W + (size_t)row0 * M + col;
    for (int r = 0; r < RPB; r += 4) {
        float4 w0 = *(const float4*)(Wp);
        float4 w1 = *(const float4*)(Wp + M);
        float4 w2 = *(const float4*)(Wp + 2 * (size_t)M);
        float4 w3 = *(const float4*)(Wp + 3 * (size_t)M);
        Wp += 4 * (size_t)M;
        #pragma unroll
        for (int b = 0; b < BB; ++b) {
            float4 xv = *(const float4*)&xs[b][r];
            acc[b].x += xv.x*w0.x + xv.y*w1.x + xv.z*w2.x + xv.w*w3.x;
            acc[b].y += xv.x*w0.y + xv.y*w1.y + xv.z*w2.y + xv.w*w3.y;
            acc[b].z += xv.x*w0.z + xv.y*w1.z + xv.z*w2.z + xv.w*w3.z;
            acc[b].w += xv.x*w0.w + xv.y*w1.w + xv.z*w2.w + xv.w*w3.w;
        }
    }
    #pragma unroll
    for (int b = 0; b < BB; ++b) {
        atomicAdd(&out[b * M + col],     acc[b].x);
        atomicAdd(&out[b * M + col + 1], acc[b].y);
        atomicAdd(&out[b * M + col + 2], acc[b].z);
        atomicAdd(&out[b * M + col + 3], acc[b].w);
    }
}

// ---------------- FIR + gating + IIR ----------------
__global__ __launch_bounds__(256) void fir_iir_k(const float* __restrict__ z,
                                                 const float* __restrict__ fir_state,
                                                 const float* __restrict__ iir_state,
                                                 const float* __restrict__ sf_weight,
                                                 const float* __restrict__ sf_bias,
                                                 const float* __restrict__ D_res,
                                                 const float* __restrict__ residues,
                                                 const float* __restrict__ log_poles,
                                                 float* __restrict__ new_fir,
                                                 float* __restrict__ new_iir,
                                                 float* __restrict__ y) {
    const int i = blockIdx.x * 256 + threadIdx.x;   // [0, B*D)
    const int b = i >> 12;          // /4096
    const int d = i & (DD - 1);
    const int h = d >> 7;           // /128
    const int p = d & (DPH - 1);
    const int j0 = h * (3 * DPH) + p;
    float zp[3];
    #pragma unroll
    for (int k = 0; k < 3; ++k) {
        int j = j0 + k * DPH;
        float u  = z[b * D3 + j];
        float f0 = fir_state[(b * D3 + j) * 2 + 0];
        float f1 = fir_state[(b * D3 + j) * 2 + 1];
        zp[k] = sf_weight[j*3+2] * u + f0 * sf_weight[j*3+0] + f1 * sf_weight[j*3+1] + sf_bias[j];
        new_fir[(b * D3 + j) * 2 + 0] = f1;
        new_fir[(b * D3 + j) * 2 + 1] = u;
    }
    float x2 = zp[0], x1 = zp[1], v = zp[2];
    float x1v = x1 * v;
    float res = 0.f;
    #pragma unroll
    for (int s = 0; s < SS; ++s) {
        float pole = expf(log_poles[d * SS + s]);
        float ni = pole * iir_state[(b * DD + d) * SS + s] + x1v;
        new_iir[(b * DD + d) * SS + s] = ni;
        res += residues[d * SS + s] * ni;
    }
    y[b * DD + d] = x2 * (res + D_res[d] * x1v);
}

// ---------------- post-attn rmsnorm; xw already holds y@out_w + x + out_b ----------------
// Also seeds out_x = xattn so the final residual is fused into the w2 GEMV atomics.
__global__ __launch_bounds__(256) void post_k(const float* __restrict__ xw,
                                              const float* __restrict__ w,
                                              float* __restrict__ out_x,
                                              float* __restrict__ xn2) {
    const int b = blockIdx.x;
    const int tid = threadIdx.x;
    float ss = 0.f;
    for (int d = tid; d < DD; d += 256) { float v = xw[b*DD + d]; ss += v*v; }
    __shared__ float red[4];
    #pragma unroll
    for (int o = 32; o > 0; o >>= 1) ss += __shfl_down(ss, o);
    if ((tid & 63) == 0) red[tid >> 6] = ss;
    __syncthreads();
    float total = red[0] + red[1] + red[2] + red[3];
    float scale = rsqrtf(total / (float)DD + 1e-6f);
    for (int d = tid; d < DD; d += 256) {
        float v = xw[b*DD + d];
        out_x[b*DD + d] = v;                 // seed final residual
        xn2[b*DD + d] = v * scale * w[d];
    }
}

extern "C" void kernel_launch(void* const* d_in, const int* in_sizes, int n_in,
                              void* d_out, int out_size, void* d_ws, size_t ws_size,
                              hipStream_t stream) {
    const float* x         = (const float*)d_in[0];
    const float* fir_state = (const float*)d_in[1];
    const float* iir_state = (const float*)d_in[2];
    const float* pre_w     = (const float*)d_in[3];
    const float* proj_w    = (const float*)d_in[4];
    const float* sf_weight = (const float*)d_in[5];
    const float* sf_bias   = (const float*)d_in[6];
    const float* D_res     = (const float*)d_in[7];
    const float* residues  = (const float*)d_in[8];
    const float* log_poles = (const float*)d_in[9];
    const float* out_w     = (const float*)d_in[10];
    const float* out_b     = (const float*)d_in[11];
    const float* post_w    = (const float*)d_in[12];
    const float* mlp_w1    = (const float*)d_in[13];
    const float* mlp_w3    = (const float*)d_in[14];
    const float* mlp_w2    = (const float*)d_in[15];

    float* ws = (float*)d_ws;
    float* z     = ws + WS_Z;
    float* a1    = ws + WS_A1;
    float* a3    = ws + WS_A3;
    float* xn1   = ws + WS_XN1;
    float* y     = ws + WS_Y;
    float* xw    = ws + WS_XW;
    float* xn2   = ws + WS_XN2;

    float* out_x   = (float*)d_out;               // [B][1][D]   32768
    float* new_fir = out_x + BB * DD;             // [B][3D][2]  196608
    float* new_iir = new_fir + BB * D3 * 2;       // [B][D][S]   524288

    // zero the atomic-accumulation region (z, a1, a3) — 1.44 MB
    hipMemsetAsync(ws, 0, (size_t)WS_ZERO_COUNT * sizeof(float), stream);

    // 1. pre-rmsnorm; also seed xw = x + out_b
    rmsnorm1_k<<<BB, 256, 0, stream>>>(x, pre_w, out_b, xn1, xw);

    // 2. z = xn1 @ proj_w   (4096 x 12288)  — 384 blocks, 32 split-K chunks
    gemv8_k<128, D3><<<dim3(D3/1024, DD/128), 256, 0, stream>>>(xn1, proj_w, z, DD);

    // 3. FIR/IIR/gating; writes new_fir, new_iir (outputs) and y
    fir_iir_k<<<(BB*DD)/256, 256, 0, stream>>>(z, fir_state, iir_state, sf_weight,
                                               sf_bias, D_res, residues, log_poles,
                                               new_fir, new_iir, y);

    // 4. xw += y @ out_w    (4096 x 4096)  — xw pre-seeded with x + out_b
    gemv8_k<64, DD><<<dim3(DD/1024, DD/64), 256, 0, stream>>>(y, out_w, xw, DD);

    // 5. xn2 = rmsnorm(xw, post_w); out_x seeded with xattn (= xw)
    post_k<<<BB, 256, 0, stream>>>(xw, post_w, out_x, xn2);

    // 6. a1 = xn2 @ mlp_w1, a3 = xn2 @ mlp_w3   (4096 x 16384, dual)
    gemv8_dual_k<256, FFF><<<dim3(FFF/1024, DD/256), 256, 0, stream>>>(xn2, mlp_w1, mlp_w3,
                                                                       a1, a3, DD);

    // 7. out_x += (silu(a1)*a3) @ mlp_w2   (16384 x 4096) — gate fused into staging
    gemv8_gate_k<256, DD><<<dim3(DD/1024, FFF/256), 256, 0, stream>>>(a1, a3, mlp_w2,
                                                                      out_x, FFF);
}